// Round 2
// baseline (4195.568 us; speedup 1.0000x reference)
//
#include <hip/hip_runtime.h>
#include <hip/hip_bf16.h>

#define B_DIM 128
#define T_DIM 512
#define I_DIMV 256
#define H_DIM 1024
#define G_DIM 4096
#define K_TOT 1280
#define C_DIM 1000
#define A_STRIDE 1288   // 1280 + 8 shorts pad (byte stride 2576, 16B aligned)

typedef __attribute__((ext_vector_type(8))) short short8;
typedef __attribute__((ext_vector_type(4))) float f32x4;
typedef __attribute__((ext_vector_type(4))) unsigned short ushort4v;
typedef __attribute__((ext_vector_type(4))) int int4v;

__device__ __forceinline__ unsigned short f2bf(float f) {
    unsigned int u = __float_as_uint(f);
    u += 0x7FFF + ((u >> 16) & 1);   // round-to-nearest-even
    return (unsigned short)(u >> 16);
}

__device__ __forceinline__ float sigmoid_f(float x) {
    return __builtin_amdgcn_rcpf(1.0f + __expf(-x));
}
__device__ __forceinline__ float tanh_f(float x) {
    return 1.0f - 2.0f * __builtin_amdgcn_rcpf(1.0f + __expf(2.0f * x));
}

// ---------------------------------------------------------------------------
// Prologue: combined bf16 weights (gate-interleaved rows p = j*4+q), bf16 x,
// combined bias, zeroed h0, zeroed flag state (in d_out). Runs every call.
// ---------------------------------------------------------------------------
__global__ void prep_kernel(const float* __restrict__ x,
                            const float* __restrict__ Wih,
                            const float* __restrict__ Whh,
                            const float* __restrict__ bih,
                            const float* __restrict__ bhh,
                            unsigned short* __restrict__ Wc,
                            unsigned short* __restrict__ xbf,
                            float* __restrict__ biasc,
                            unsigned short* __restrict__ h0,
                            unsigned* __restrict__ bar)
{
    const int tid = blockIdx.x * blockDim.x + threadIdx.x;
    const int nth = gridDim.x * blockDim.x;

    const int WcN4 = G_DIM * K_TOT / 4;
    for (int i = tid; i < WcN4; i += nth) {
        int p = i / (K_TOT / 4);
        int k = (i - p * (K_TOT / 4)) * 4;
        int j = p >> 2, q = p & 3;
        int r = q * H_DIM + j;
        const float* src = (k < H_DIM) ? (Whh + (size_t)r * H_DIM + k)
                                       : (Wih + (size_t)r * I_DIMV + (k - H_DIM));
        f32x4 v = *(const f32x4*)src;
        ushort4v o;
        o.x = f2bf(v.x); o.y = f2bf(v.y); o.z = f2bf(v.z); o.w = f2bf(v.w);
        *(ushort4v*)(Wc + (size_t)i * 4) = o;
    }
    const int xN4 = B_DIM * T_DIM * I_DIMV / 4;
    for (int i = tid; i < xN4; i += nth) {
        f32x4 v = *(const f32x4*)(x + (size_t)i * 4);
        ushort4v o;
        o.x = f2bf(v.x); o.y = f2bf(v.y); o.z = f2bf(v.z); o.w = f2bf(v.w);
        *(ushort4v*)(xbf + (size_t)i * 4) = o;
    }
    for (int p = tid; p < G_DIM; p += nth) {
        int j = p >> 2, q = p & 3;
        int r = q * H_DIM + j;
        biasc[p] = bih[r] + bhh[r];
    }
    const int hN4 = B_DIM * H_DIM / 4;
    for (int i = tid; i < hN4; i += nth) {
        ushort4v z = {0, 0, 0, 0};
        *(ushort4v*)(h0 + (size_t)i * 4) = z;
    }
    // flags: 8 groups x 32 producers, stride 32 u32 (128 B) each = 8192 u32
    for (int i = tid; i < 8192; i += nth) bar[i] = 0;
}

// ---------------------------------------------------------------------------
// Persistent LSTM, plain launch. 256 WGs x 256 threads; co-residency is
// structural (LDS 41KB, 1 WG/CU by VGPR budget; 256 WGs on 256 CUs -> all
// dispatched immediately).
// WG: m_blk = wgid>>5 -> batches [16*m_blk, +16)
//     n_blk = wgid&31 -> hidden [32*n_blk, +32) == gate rows [128*n_blk,+128)
//                        == A-panel K-chunk c = n_blk (own slice, LDS-local)
// Sync: one-sided per-producer flags (no rendezvous). After the drain
// __syncthreads (each wave's vmcnt(0) acks its sc0sc1 h stores at the MALL),
// tid0 release-stores flag[m][n] = t+1. Consumers poll the 32 flags
// lane-parallel (ballot) then stage only the 31 foreign 1KB slices.
// Skew safety: flag[q] >= t  =>  q finished iter t-1  =>  q already read all
// h_{t-2} slices, so overwriting h_{t-2}'s buffer (2-buffer ping-pong) while
// at most 1 iteration ahead is race-free (same invariant the barrier gave).
// RACE FIX vs prior attempt: the own-slice LDS write is deferred until AFTER
// the end-of-iteration drain __syncthreads (val carried in registers), so no
// wave overwrites h_t in LDS while another wave's K-loop still reads it. The
// next iteration's staging __syncthreads orders it before all K-loop reads.
// ---------------------------------------------------------------------------
__global__ __launch_bounds__(256, 1)
void lstm_grid(const unsigned short* __restrict__ Wc,
               const unsigned short* __restrict__ xbf,
               const float* __restrict__ biasc,
               unsigned short* __restrict__ hb0,
               unsigned short* __restrict__ hb1,
               float* __restrict__ hf32,
               unsigned* __restrict__ bar)
{
    __shared__ __align__(16) unsigned short Alds[16 * A_STRIDE];  // 41,216 B

    const int tid   = threadIdx.x;
    const int wgid  = blockIdx.x;
    const int m_blk = wgid >> 5;
    const int n_blk = wgid & 31;
    const int b0 = m_blk * 16;         // batch rows [b0, b0+16)
    const int p0 = n_blk * 128;        // gate rows  [p0, p0+128)
    const int j0 = n_blk * 32;         // hidden cols [j0, j0+32)

    const int wid  = tid >> 6;         // wave -> gate cols [wid*32, +32)
    const int lane = tid & 63;
    const int cl   = lane & 15;
    const int quad = lane >> 4;
    const int q_g  = cl & 3;           // gate: 0=i 1=f 2=g 3=o
    const int jl   = cl >> 2;

    const float bias0 = biasc[p0 + wid * 32 + cl];
    const float bias1 = biasc[p0 + wid * 32 + 16 + cl];

    // W slice in registers: 2 subtiles x 40 k-chunks = 80 x short8 (320 regs)
    short8 Wreg[80];
    {
        const unsigned short* w0 = Wc + (size_t)(p0 + wid * 32 + cl) * K_TOT + quad * 8;
        const unsigned short* w1 = w0 + (size_t)16 * K_TOT;
        #pragma unroll
        for (int c = 0; c < 40; ++c) {
            Wreg[c]      = *(const short8*)(w0 + c * 32);
            Wreg[40 + c] = *(const short8*)(w1 + c * 32);
        }
    }

    // flags (in d_out; overwritten by fc_kernel afterwards)
    unsigned* const gflags    = bar + m_blk * 1024;     // 32 flags, stride 32 u32
    unsigned* const own_flag  = gflags + n_blk * 32;
    const unsigned* const poll_flag = gflags + lane * 32;   // valid for lane<32

    // own h-chunk (A cols [j0, j0+32)) starts as h0 = 0; never reloaded from
    // global -- the pointwise phase feeds it straight into LDS each step.
    if (wid == 0) {
        const int row = lane >> 2;
        const int c8  = (lane & 3) * 8;
        int4v z = {0, 0, 0, 0};
        *(int4v*)(&Alds[row * A_STRIDE + j0 + c8]) = z;
    }

    const int nsl  = (wid < 3) ? 8 : 7;   // foreign slices staged by this wave
    const int srow = lane >> 2;           // slice load: row 0..15
    const int scol = (lane & 3) * 8;      // slice load: col-chunk (shorts)

    float c0v = 0.0f, c1v = 0.0f;         // cell state: 1 cell per lane per subtile

    for (int t = 0; t < T_DIM; ++t) {
        const unsigned short* hread = (t & 1) ? hb1 : hb0;
        unsigned short* hwrite      = (t & 1) ? hb0 : hb1;

        // ---- x_t loads (cached path; independent of h, overlaps the poll) ----
        short8 xtmp[2];
        #pragma unroll
        for (int u = 0; u < 2; ++u) {
            const int idx = u * 256 + tid;
            const int row = idx >> 5;
            const int col = (idx & 31) * 8;
            xtmp[u] = *(const short8*)(xbf + (size_t)(b0 + row) * (T_DIM * I_DIMV)
                                       + (size_t)t * I_DIMV + col);
        }

        // ---- wait for all producers of h_t (lane-parallel flag poll) ----
        if (t > 0) {
            while (true) {
                unsigned v = (lane < 32)
                    ? __hip_atomic_load(poll_flag, __ATOMIC_RELAXED,
                                        __HIP_MEMORY_SCOPE_AGENT)
                    : 0xFFFFFFFFu;
                if (__ballot(v >= (unsigned)t) == ~0ull) break;
                __builtin_amdgcn_s_sleep(1);
            }
        }

        // ---- stage this wave's foreign slices, MALL-direct (1 KB each) ----
        int4v stmp[8];
        #pragma unroll
        for (int j = 0; j < 8; ++j) {
            if (j < nsl) {
                const int q = (n_blk + wid + 1 + 4 * j) & 31;
                const unsigned short* src =
                    hread + (size_t)(b0 + srow) * H_DIM + q * 32 + scol;
                asm volatile("global_load_dwordx4 %0, %1, off sc0 sc1"
                             : "=v"(stmp[j]) : "v"(src) : "memory");
            }
        }
        asm volatile("s_waitcnt vmcnt(0)" ::: "memory");
        #pragma unroll
        for (int j = 0; j < 8; ++j) {
            if (j < nsl) {
                const int q = (n_blk + wid + 1 + 4 * j) & 31;
                *(int4v*)(&Alds[srow * A_STRIDE + q * 32 + scol]) = stmp[j];
            }
        }
        #pragma unroll
        for (int u = 0; u < 2; ++u) {
            const int idx = u * 256 + tid;
            const int row = idx >> 5;
            const int col = (idx & 31) * 8;
            *(short8*)(&Alds[row * A_STRIDE + 1024 + col]) = xtmp[u];
        }
        __syncthreads();   // also orders last iter's own-slice LDS write

        // ---- K loop: 40 chunks x 2 gate-subtiles, W from registers ----
        f32x4 acc0 = {0.f, 0.f, 0.f, 0.f};
        f32x4 acc1 = {0.f, 0.f, 0.f, 0.f};
        #pragma unroll
        for (int c = 0; c < 40; ++c) {
            short8 a = *(const short8*)(&Alds[cl * A_STRIDE + c * 32 + quad * 8]);
            acc0 = __builtin_amdgcn_mfma_f32_16x16x32_bf16(a, Wreg[c],      acc0, 0, 0, 0);
            acc1 = __builtin_amdgcn_mfma_f32_16x16x32_bf16(a, Wreg[40 + c], acc1, 0, 0, 0);
        }

        // ---- pointwise: 4x4 xor-transpose within each gate-quad ----
        // lane q_g owns cell (b = quad*4+q_g, j = j0+wid*8+s*4+jl) with gates
        // in slots 0..3 -- 2 cells/lane instead of 8 redundant ones.
        float hn[2];
        #pragma unroll
        for (int s = 0; s < 2; ++s) {
            const f32x4 accv = s ? acc1 : acc0;
            const float bs   = s ? bias1 : bias0;
            float e[4];
            #pragma unroll
            for (int r = 0; r < 4; ++r) e[r] = accv[r] + bs;
            float t1[4];
            #pragma unroll
            for (int r = 0; r < 4; ++r) t1[r] = __shfl_xor(e[r ^ 1], 1);
            #pragma unroll
            for (int r = 0; r < 4; ++r) e[r] = ((q_g ^ r) & 1) ? t1[r] : e[r];
            float t2[4];
            #pragma unroll
            for (int r = 0; r < 4; ++r) t2[r] = __shfl_xor(e[r ^ 2], 2);
            #pragma unroll
            for (int r = 0; r < 4; ++r) e[r] = ((q_g ^ r) & 2) ? t2[r] : e[r];

            const float ig = sigmoid_f(e[0]);
            const float fg = sigmoid_f(e[1]);
            const float gg = tanh_f(e[2]);
            const float og = sigmoid_f(e[3]);
            const float cp = s ? c1v : c0v;
            const float cn = fg * cp + ig * gg;
            if (s) c1v = cn; else c0v = cn;
            hn[s] = og * tanh_f(cn);
        }

        // ---- pack 8 cols (both subtiles) -> one 16B value per cell-row ----
        const unsigned short hb16_0 = f2bf(hn[0]);
        const unsigned short hb16_1 = f2bf(hn[1]);
        unsigned p32_0 = (unsigned)hb16_0 |
            ((unsigned)(unsigned short)__shfl_xor((int)hb16_0, 4) << 16);
        unsigned p32_1 = (unsigned)hb16_1 |
            ((unsigned)(unsigned short)__shfl_xor((int)hb16_1, 4) << 16);
        unsigned hi_0 = (unsigned)__shfl_xor((int)p32_0, 8);
        unsigned hi_1 = (unsigned)__shfl_xor((int)p32_1, 8);

        int4v val;
        val.x = (int)p32_0; val.y = (int)hi_0;
        val.z = (int)p32_1; val.w = (int)hi_1;
        const int brow = quad * 4 + q_g;

        if (jl == 0 && t + 1 < T_DIM) {    // 16 lanes/wave: (quad, q_g)
            unsigned short* dst =
                hwrite + (size_t)(b0 + brow) * H_DIM + j0 + wid * 8;
            asm volatile("global_store_dwordx4 %0, %1, off sc0 sc1"
                         :: "v"(dst), "v"(val) : "memory");
        }
        if (t == T_DIM - 1) {
            const size_t base = (size_t)(b0 + brow) * H_DIM + j0 + wid * 8 + jl;
            hf32[base]     = hn[0];
            hf32[base + 4] = hn[1];
            // hf32 stores drain at kernel end (dispatch boundary)
        }

        // drain: each wave's vmcnt(0)/lgkmcnt(0) before s_barrier => all
        // sc0sc1 h stores acked at the MALL; all K-loop LDS reads complete
        __syncthreads();

        if (t + 1 < T_DIM) {
            if (tid == 0) {
                __hip_atomic_store(own_flag, (unsigned)(t + 1), __ATOMIC_RELEASE,
                                   __HIP_MEMORY_SCOPE_AGENT);
            }
            // own slice straight into LDS for next step (race-free: all waves
            // passed the drain barrier; next staging barrier orders it before
            // any K-loop read of iteration t+1)
            if (jl == 0) {
                *(int4v*)(&Alds[brow * A_STRIDE + j0 + wid * 8]) = val;
            }
        }
    }
}

// ---------------------------------------------------------------------------
// Final fc: out[128,1000] = h @ fc_W^T + fc_b, fp32. Overwrites the flag
// region of d_out with real results (runs strictly after lstm_grid).
// ---------------------------------------------------------------------------
__global__ __launch_bounds__(256)
void fc_kernel(const float* __restrict__ hf32,
               const float* __restrict__ fcW,
               const float* __restrict__ fcb,
               float* __restrict__ out)
{
    __shared__ __align__(16) float hs[16 * 256];
    const int tid = threadIdx.x;
    const int b0 = blockIdx.x * 16;
    const int o0 = blockIdx.y * 64;
    const int to = tid & 63;
    const int tb = tid >> 6;
    const int o  = o0 + to;
    const bool active = (o < C_DIM);

    float acc[4] = {0.f, 0.f, 0.f, 0.f};

    for (int jc = 0; jc < H_DIM; jc += 256) {
        __syncthreads();
        {
            const int row = tid >> 4;
            const int c0  = (tid & 15) * 16;
            #pragma unroll
            for (int u = 0; u < 4; ++u) {
                *(f32x4*)(&hs[row * 256 + c0 + u * 4]) =
                    *(const f32x4*)(hf32 + (size_t)(b0 + row) * H_DIM + jc + c0 + u * 4);
            }
        }
        __syncthreads();
        if (active) {
            for (int j4 = 0; j4 < 256; j4 += 4) {
                f32x4 wv = *(const f32x4*)(fcW + (size_t)o * H_DIM + jc + j4);
                #pragma unroll
                for (int bb = 0; bb < 4; ++bb) {
                    f32x4 hv = *(const f32x4*)(&hs[(tb * 4 + bb) * 256 + j4]);
                    acc[bb] += wv.x * hv.x + wv.y * hv.y + wv.z * hv.z + wv.w * hv.w;
                }
            }
        }
    }
    if (active) {
        const float bias = fcb[o];
        #pragma unroll
        for (int bb = 0; bb < 4; ++bb) {
            out[(size_t)(b0 + tb * 4 + bb) * C_DIM + o] = acc[bb] + bias;
        }
    }
}

extern "C" void kernel_launch(void* const* d_in, const int* in_sizes, int n_in,
                              void* d_out, int out_size, void* d_ws, size_t ws_size,
                              hipStream_t stream)
{
    const float* x   = (const float*)d_in[0];
    const float* Wih = (const float*)d_in[1];
    const float* Whh = (const float*)d_in[2];
    const float* bih = (const float*)d_in[3];
    const float* bhh = (const float*)d_in[4];
    const float* fcW = (const float*)d_in[5];
    const float* fcb = (const float*)d_in[6];
    float* out = (float*)d_out;

    char* ws = (char*)d_ws;
    unsigned short* Wc  = (unsigned short*)(ws + 0);         // 10,485,760 B
    unsigned short* xbf = (unsigned short*)(ws + 10485760);  // 33,554,432 B
    float* biasc        = (float*)(ws + 44040192);           //     16,384 B
    unsigned short* hb0 = (unsigned short*)(ws + 44056576);  //    262,144 B
    unsigned short* hb1 = (unsigned short*)(ws + 44318720);  //    262,144 B
    float* hf32         = (float*)(ws + 44580864);           //    524,288 B
    // total ws use: 45,105,152 B (identical to the proven layout)
    unsigned* bar       = (unsigned*)d_out;  // 32 KB of d_out (512,000 B);
                                             // fc_kernel overwrites it last.

    hipLaunchKernelGGL(prep_kernel, dim3(1024), dim3(256), 0, stream,
                       x, Wih, Whh, bih, bhh, Wc, xbf, biasc, hb0, bar);

    hipLaunchKernelGGL(lstm_grid, dim3(256), dim3(256), 0, stream,
                       Wc, xbf, biasc, hb0, hb1, hf32, bar);

    hipLaunchKernelGGL(fc_kernel, dim3(8, 16), dim3(256), 0, stream,
                       hf32, fcW, fcb, out);
}

// Round 3
// 2432.850 us; speedup vs baseline: 1.7245x; 1.7245x over previous
//
#include <hip/hip_runtime.h>
#include <hip/hip_bf16.h>

#define B_DIM 128
#define T_DIM 512
#define I_DIMV 256
#define H_DIM 1024
#define G_DIM 4096
#define K_TOT 1280
#define C_DIM 1000
#define A_STRIDE 1288   // 1280 + 8 shorts pad (byte stride 2576, 16B aligned)

typedef __attribute__((ext_vector_type(8))) short short8;
typedef __attribute__((ext_vector_type(4))) float f32x4;
typedef __attribute__((ext_vector_type(4))) unsigned short ushort4v;
typedef __attribute__((ext_vector_type(4))) int int4v;

__device__ __forceinline__ unsigned short f2bf(float f) {
    unsigned int u = __float_as_uint(f);
    u += 0x7FFF + ((u >> 16) & 1);   // round-to-nearest-even
    return (unsigned short)(u >> 16);
}

__device__ __forceinline__ float sigmoid_f(float x) {
    return __builtin_amdgcn_rcpf(1.0f + __expf(-x));
}
__device__ __forceinline__ float tanh_f(float x) {
    return 1.0f - 2.0f * __builtin_amdgcn_rcpf(1.0f + __expf(2.0f * x));
}

// ---------------------------------------------------------------------------
// Prologue: combined bf16 weights (gate-interleaved rows p = j*4+q), bf16 x,
// combined bias, zeroed h0, zeroed barrier state (in d_out). Runs every call.
// ---------------------------------------------------------------------------
__global__ void prep_kernel(const float* __restrict__ x,
                            const float* __restrict__ Wih,
                            const float* __restrict__ Whh,
                            const float* __restrict__ bih,
                            const float* __restrict__ bhh,
                            unsigned short* __restrict__ Wc,
                            unsigned short* __restrict__ xbf,
                            float* __restrict__ biasc,
                            unsigned short* __restrict__ h0,
                            unsigned* __restrict__ bar)
{
    const int tid = blockIdx.x * blockDim.x + threadIdx.x;
    const int nth = gridDim.x * blockDim.x;

    const int WcN4 = G_DIM * K_TOT / 4;
    for (int i = tid; i < WcN4; i += nth) {
        int p = i / (K_TOT / 4);
        int k = (i - p * (K_TOT / 4)) * 4;
        int j = p >> 2, q = p & 3;
        int r = q * H_DIM + j;
        const float* src = (k < H_DIM) ? (Whh + (size_t)r * H_DIM + k)
                                       : (Wih + (size_t)r * I_DIMV + (k - H_DIM));
        f32x4 v = *(const f32x4*)src;
        ushort4v o;
        o.x = f2bf(v.x); o.y = f2bf(v.y); o.z = f2bf(v.z); o.w = f2bf(v.w);
        *(ushort4v*)(Wc + (size_t)i * 4) = o;
    }
    const int xN4 = B_DIM * T_DIM * I_DIMV / 4;
    for (int i = tid; i < xN4; i += nth) {
        f32x4 v = *(const f32x4*)(x + (size_t)i * 4);
        ushort4v o;
        o.x = f2bf(v.x); o.y = f2bf(v.y); o.z = f2bf(v.z); o.w = f2bf(v.w);
        *(ushort4v*)(xbf + (size_t)i * 4) = o;
    }
    for (int p = tid; p < G_DIM; p += nth) {
        int j = p >> 2, q = p & 3;
        int r = q * H_DIM + j;
        biasc[p] = bih[r] + bhh[r];
    }
    const int hN4 = B_DIM * H_DIM / 4;
    for (int i = tid; i < hN4; i += nth) {
        ushort4v z = {0, 0, 0, 0};
        *(ushort4v*)(h0 + (size_t)i * 4) = z;
    }
    for (int i = tid; i < 1024; i += nth) bar[i] = 0;
}

// ---------------------------------------------------------------------------
// Per-group 32-way barrier (proven R0 form). Batch groups are independent;
// only the 32 WGs sharing batch rows [16g,16g+16) must sync. All shared data
// (h) moves via sc0+sc1 (MALL-direct) accesses, and __syncthreads' vmcnt
// drain orders h stores before the arrival RMW.
// bar (in d_out): per group g: [64g] counter, [64g+32] generation.
// ---------------------------------------------------------------------------
__device__ __forceinline__ void group_barrier(unsigned* bar, unsigned epoch, int grp) {
    __syncthreads();   // every wave's sc0sc1 h stores acked at the MALL
    if (threadIdx.x == 0) {
        unsigned* cnt = bar + 64 * grp;
        unsigned* gen = bar + 64 * grp + 32;
        unsigned old = __hip_atomic_fetch_add(cnt, 1u, __ATOMIC_RELAXED,
                                              __HIP_MEMORY_SCOPE_AGENT);
        if (old == 31u) {   // last arriver: reset + release generation
            __hip_atomic_store(cnt, 0u, __ATOMIC_RELAXED,
                               __HIP_MEMORY_SCOPE_AGENT);
            __hip_atomic_store(gen, epoch, __ATOMIC_RELEASE,
                               __HIP_MEMORY_SCOPE_AGENT);
        } else {
            while (__hip_atomic_load(gen, __ATOMIC_RELAXED,
                                     __HIP_MEMORY_SCOPE_AGENT) < epoch)
                __builtin_amdgcn_s_sleep(1);
        }
    }
    __syncthreads();
}

// ---------------------------------------------------------------------------
// Persistent LSTM, plain launch. 256 WGs x 256 threads; co-residency is
// structural (LDS 41KB, 1 WG/CU by VGPR budget; 256 WGs on 256 CUs -> all
// dispatched immediately).
// WG: m_blk = wgid>>5 -> batches [16*m_blk, +16) (= sync group)
//     n_blk = wgid&31 -> hidden [32*n_blk, +32) == gate rows [128*n_blk,+128)
// W slice in registers for all 512 steps. h exchanged MALL-direct (sc0 sc1).
// Sync/staging: EXACT proven R0 form (rendezvous barrier + full-panel h
// reload). Changes vs R0, both validated in R2: (a) 4x4 xor-transpose
// pointwise -- each lane computes 2 cells with 1 transcendental set instead
// of 8 redundant ones (halves serial VALU); (b) packed 16B dwordx4 h-store
// (halves HBM write amplification vs 2x dwordx2).
// ---------------------------------------------------------------------------
__global__ __launch_bounds__(256, 1)
void lstm_grid(const unsigned short* __restrict__ Wc,
               const unsigned short* __restrict__ xbf,
               const float* __restrict__ biasc,
               unsigned short* __restrict__ hb0,
               unsigned short* __restrict__ hb1,
               float* __restrict__ hf32,
               unsigned* __restrict__ bar)
{
    __shared__ __align__(16) unsigned short Alds[16 * A_STRIDE];  // 41,216 B

    const int tid   = threadIdx.x;
    const int wgid  = blockIdx.x;
    const int m_blk = wgid >> 5;
    const int n_blk = wgid & 31;
    const int b0 = m_blk * 16;         // batch rows [b0, b0+16)
    const int p0 = n_blk * 128;        // gate rows  [p0, p0+128)
    const int j0 = n_blk * 32;         // hidden cols [j0, j0+32)

    const int wid  = tid >> 6;         // wave -> gate cols [wid*32, +32)
    const int lane = tid & 63;
    const int cl   = lane & 15;
    const int quad = lane >> 4;
    const int q_g  = cl & 3;           // gate: 0=i 1=f 2=g 3=o
    const int jl   = cl >> 2;

    const float bias0 = biasc[p0 + wid * 32 + cl];
    const float bias1 = biasc[p0 + wid * 32 + 16 + cl];

    // W slice in registers: 2 subtiles x 40 k-chunks = 80 x short8 (320 regs)
    short8 Wreg[80];
    {
        const unsigned short* w0 = Wc + (size_t)(p0 + wid * 32 + cl) * K_TOT + quad * 8;
        const unsigned short* w1 = w0 + (size_t)16 * K_TOT;
        #pragma unroll
        for (int c = 0; c < 40; ++c) {
            Wreg[c]      = *(const short8*)(w0 + c * 32);
            Wreg[40 + c] = *(const short8*)(w1 + c * 32);
        }
    }

    float c0v = 0.0f, c1v = 0.0f;      // cell state: 1 cell/lane per subtile

    for (int t = 0; t < T_DIM; ++t) {
        const unsigned short* hread = (t & 1) ? hb1 : hb0;
        unsigned short* hwrite      = (t & 1) ? hb0 : hb1;

        // ---- stage A panel: h[16x1024] MALL-direct + x_t[16x256] cached ----
        int4v htmp[8];
        #pragma unroll
        for (int u = 0; u < 8; ++u) {
            const int idx = u * 256 + tid;          // 0..2047
            const int row = idx >> 7;               // 0..15
            const int col = (idx & 127) * 8;        // 0..1016
            const unsigned short* src = hread + (size_t)(b0 + row) * H_DIM + col;
            asm volatile("global_load_dwordx4 %0, %1, off sc0 sc1"
                         : "=v"(htmp[u]) : "v"(src) : "memory");
        }
        short8 xtmp[2];
        #pragma unroll
        for (int u = 0; u < 2; ++u) {
            const int idx = u * 256 + tid;          // 0..511
            const int row = idx >> 5;               // 0..15
            const int col = (idx & 31) * 8;         // 0..248
            xtmp[u] = *(const short8*)(xbf + (size_t)(b0 + row) * (T_DIM * I_DIMV)
                                       + (size_t)t * I_DIMV + col);
        }
        asm volatile("s_waitcnt vmcnt(0)" ::: "memory");
        #pragma unroll
        for (int u = 0; u < 8; ++u) {
            const int idx = u * 256 + tid;
            const int row = idx >> 7;
            const int col = (idx & 127) * 8;
            *(int4v*)(&Alds[row * A_STRIDE + col]) = htmp[u];
        }
        #pragma unroll
        for (int u = 0; u < 2; ++u) {
            const int idx = u * 256 + tid;
            const int row = idx >> 5;
            const int col = (idx & 31) * 8;
            *(short8*)(&Alds[row * A_STRIDE + 1024 + col]) = xtmp[u];
        }
        __syncthreads();

        // ---- K loop: 40 chunks x 2 gate-subtiles, W from registers ----
        f32x4 acc0 = {0.f, 0.f, 0.f, 0.f};
        f32x4 acc1 = {0.f, 0.f, 0.f, 0.f};
        #pragma unroll
        for (int c = 0; c < 40; ++c) {
            short8 a = *(const short8*)(&Alds[cl * A_STRIDE + c * 32 + quad * 8]);
            acc0 = __builtin_amdgcn_mfma_f32_16x16x32_bf16(a, Wreg[c],      acc0, 0, 0, 0);
            acc1 = __builtin_amdgcn_mfma_f32_16x16x32_bf16(a, Wreg[40 + c], acc1, 0, 0, 0);
        }

        // ---- pointwise: 4x4 xor-transpose within each gate-quad ----
        // lane q_g owns cell (b = quad*4+q_g, j = j0+wid*8+s*4+jl) with gates
        // in slots 0..3 -- 2 cells/lane instead of 8 redundant ones.
        float hn[2];
        #pragma unroll
        for (int s = 0; s < 2; ++s) {
            const f32x4 accv = s ? acc1 : acc0;
            const float bs   = s ? bias1 : bias0;
            float e[4];
            #pragma unroll
            for (int r = 0; r < 4; ++r) e[r] = accv[r] + bs;
            float t1[4];
            #pragma unroll
            for (int r = 0; r < 4; ++r) t1[r] = __shfl_xor(e[r ^ 1], 1);
            #pragma unroll
            for (int r = 0; r < 4; ++r) e[r] = ((q_g ^ r) & 1) ? t1[r] : e[r];
            float t2[4];
            #pragma unroll
            for (int r = 0; r < 4; ++r) t2[r] = __shfl_xor(e[r ^ 2], 2);
            #pragma unroll
            for (int r = 0; r < 4; ++r) e[r] = ((q_g ^ r) & 2) ? t2[r] : e[r];

            const float ig = sigmoid_f(e[0]);
            const float fg = sigmoid_f(e[1]);
            const float gg = tanh_f(e[2]);
            const float og = sigmoid_f(e[3]);
            const float cp = s ? c1v : c0v;
            const float cn = fg * cp + ig * gg;
            if (s) c1v = cn; else c0v = cn;
            hn[s] = og * tanh_f(cn);
        }

        // ---- pack 8 cols (both subtiles) -> one 16B store per cell-row ----
        const unsigned short hb16_0 = f2bf(hn[0]);
        const unsigned short hb16_1 = f2bf(hn[1]);
        unsigned p32_0 = (unsigned)hb16_0 |
            ((unsigned)(unsigned short)__shfl_xor((int)hb16_0, 4) << 16);
        unsigned p32_1 = (unsigned)hb16_1 |
            ((unsigned)(unsigned short)__shfl_xor((int)hb16_1, 4) << 16);
        unsigned hi_0 = (unsigned)__shfl_xor((int)p32_0, 8);
        unsigned hi_1 = (unsigned)__shfl_xor((int)p32_1, 8);

        const int brow = quad * 4 + q_g;
        if (jl == 0 && t + 1 < T_DIM) {    // 16 lanes/wave: (quad, q_g)
            int4v val;
            val.x = (int)p32_0; val.y = (int)hi_0;
            val.z = (int)p32_1; val.w = (int)hi_1;
            unsigned short* dst =
                hwrite + (size_t)(b0 + brow) * H_DIM + j0 + wid * 8;
            asm volatile("global_store_dwordx4 %0, %1, off sc0 sc1"
                         :: "v"(dst), "v"(val) : "memory");
        }
        if (t == T_DIM - 1) {
            const size_t base = (size_t)(b0 + brow) * H_DIM + j0 + wid * 8 + jl;
            hf32[base]     = hn[0];
            hf32[base + 4] = hn[1];
            // hf32 stores drain at kernel end (dispatch boundary)
        }

        if (t + 1 < T_DIM)
            group_barrier(bar, (unsigned)(t + 1), m_blk);
        // final step: hf32 stores drain at kernel end (dispatch boundary)
    }
}

// ---------------------------------------------------------------------------
// Final fc: out[128,1000] = h @ fc_W^T + fc_b, fp32. Overwrites the bar
// region of d_out with real results (runs strictly after lstm_grid).
// ---------------------------------------------------------------------------
__global__ __launch_bounds__(256)
void fc_kernel(const float* __restrict__ hf32,
               const float* __restrict__ fcW,
               const float* __restrict__ fcb,
               float* __restrict__ out)
{
    __shared__ __align__(16) float hs[16 * 256];
    const int tid = threadIdx.x;
    const int b0 = blockIdx.x * 16;
    const int o0 = blockIdx.y * 64;
    const int to = tid & 63;
    const int tb = tid >> 6;
    const int o  = o0 + to;
    const bool active = (o < C_DIM);

    float acc[4] = {0.f, 0.f, 0.f, 0.f};

    for (int jc = 0; jc < H_DIM; jc += 256) {
        __syncthreads();
        {
            const int row = tid >> 4;
            const int c0  = (tid & 15) * 16;
            #pragma unroll
            for (int u = 0; u < 4; ++u) {
                *(f32x4*)(&hs[row * 256 + c0 + u * 4]) =
                    *(const f32x4*)(hf32 + (size_t)(b0 + row) * H_DIM + jc + c0 + u * 4);
            }
        }
        __syncthreads();
        if (active) {
            for (int j4 = 0; j4 < 256; j4 += 4) {
                f32x4 wv = *(const f32x4*)(fcW + (size_t)o * H_DIM + jc + j4);
                #pragma unroll
                for (int bb = 0; bb < 4; ++bb) {
                    f32x4 hv = *(const f32x4*)(&hs[(tb * 4 + bb) * 256 + j4]);
                    acc[bb] += wv.x * hv.x + wv.y * hv.y + wv.z * hv.z + wv.w * hv.w;
                }
            }
        }
    }
    if (active) {
        const float bias = fcb[o];
        #pragma unroll
        for (int bb = 0; bb < 4; ++bb) {
            out[(size_t)(b0 + tb * 4 + bb) * C_DIM + o] = acc[bb] + bias;
        }
    }
}

extern "C" void kernel_launch(void* const* d_in, const int* in_sizes, int n_in,
                              void* d_out, int out_size, void* d_ws, size_t ws_size,
                              hipStream_t stream)
{
    const float* x   = (const float*)d_in[0];
    const float* Wih = (const float*)d_in[1];
    const float* Whh = (const float*)d_in[2];
    const float* bih = (const float*)d_in[3];
    const float* bhh = (const float*)d_in[4];
    const float* fcW = (const float*)d_in[5];
    const float* fcb = (const float*)d_in[6];
    float* out = (float*)d_out;

    char* ws = (char*)d_ws;
    unsigned short* Wc  = (unsigned short*)(ws + 0);         // 10,485,760 B
    unsigned short* xbf = (unsigned short*)(ws + 10485760);  // 33,554,432 B
    float* biasc        = (float*)(ws + 44040192);           //     16,384 B
    unsigned short* hb0 = (unsigned short*)(ws + 44056576);  //    262,144 B
    unsigned short* hb1 = (unsigned short*)(ws + 44318720);  //    262,144 B
    float* hf32         = (float*)(ws + 44580864);           //    524,288 B
    // total ws use: 45,105,152 B (identical to the proven layout)
    unsigned* bar       = (unsigned*)d_out;  // 4 KB of d_out (512,000 B);
                                             // fc_kernel overwrites it last.

    hipLaunchKernelGGL(prep_kernel, dim3(1024), dim3(256), 0, stream,
                       x, Wih, Whh, bih, bhh, Wc, xbf, biasc, hb0, bar);

    hipLaunchKernelGGL(lstm_grid, dim3(256), dim3(256), 0, stream,
                       Wc, xbf, biasc, hb0, hb1, hf32, bar);

    hipLaunchKernelGGL(fc_kernel, dim3(8, 16), dim3(256), 0, stream,
                       hf32, fcW, fcb, out);
}